// Round 5
// baseline (230.123 us; speedup 1.0000x reference)
//
#include <hip/hip_runtime.h>

// Problem constants: B=4, N=2048, F=D=128, H=4.
#define NB 4
#define NN 2048
#define ND 128
#define NH 4

typedef short short8 __attribute__((ext_vector_type(8)));
typedef float floatx4 __attribute__((ext_vector_type(4)));

__device__ __forceinline__ short f2bf(float f){
  unsigned u = __float_as_uint(f);
  u += 0x7FFFu + ((u >> 16) & 1u);   // round-to-nearest-even
  return (short)(u >> 16);
}
__device__ __forceinline__ float bf2f(short s){
  unsigned u = ((unsigned)(unsigned short)s) << 16;
  return __uint_as_float(u);
}
__device__ __forceinline__ int pack2(short lo, short hi){
  return ((int)(unsigned short)hi << 16) | (int)(unsigned short)lo;
}

// ---------------- K0: WT[d][f] = W[f][d]; attnT[h][e][d] = attn[h][d][e] (bf16) ----
__global__ void k0_transpose(const float* __restrict__ W, const float* __restrict__ attn,
                             short* __restrict__ WT, short* __restrict__ attnT){
  int mat = blockIdx.x;                       // 0 = W, 1..4 = attn heads
  const float* src = (mat == 0) ? W : (attn + (mat - 1) * 16384);
  short* dst = (mat == 0) ? WT : (attnT + (mat - 1) * 16384);
  __shared__ short tile[128 * 130];
  int t = threadIdx.x;
  for (int k = 0; k < 64; ++k){               // coalesced read, transposed LDS write
    int idx = k * 256 + t;
    int r = idx >> 7, c = idx & 127;
    tile[c * 130 + r] = f2bf(src[idx]);
  }
  __syncthreads();
  for (int k = 0; k < 8; ++k){                // coalesced vector write out
    int g = k * 256 + t;
    int r = g >> 4, c8 = g & 15;
    short8 v;
    #pragma unroll
    for (int j = 0; j < 8; ++j) v[j] = tile[r * 130 + c8 * 8 + j];
    *(short8*)&dst[r * 128 + c8 * 8] = v;
  }
}

// ---------------- K1: Xp = X @ W + bias ; writes BOTH Xp and XpT (coalesced) ------
__global__ __launch_bounds__(256) void k1_xp(const float* __restrict__ X,
                                             const short* __restrict__ WT,
                                             const float* __restrict__ bias,
                                             short* __restrict__ Xp,
                                             short* __restrict__ XpT){
  int bid = blockIdx.x;                       // 128 = 4b * 32 i-tiles
  int b = bid >> 5, i0 = (bid & 31) << 6;
  int t = threadIdx.x, w = t >> 6, lane = t & 63, lq = lane >> 4, lc = lane & 15;
  __shared__ __align__(16) short ldsB[16384]; // B-staging, later reused as [128 d][72] tile
  #pragma unroll
  for (int c = 0; c < 8; ++c){
    int q = c * 256 + t; int fblk = q >> 7; int d = q & 127;
    *(short8*)&ldsB[q * 8] = *(const short8*)&WT[d * 128 + fblk * 8];
  }
  short8 af[4][4];
  #pragma unroll
  for (int ib = 0; ib < 4; ++ib)
    #pragma unroll
    for (int k = 0; k < 4; ++k){
      const float* xp = &X[(b * NN + i0 + ib * 16 + lc) * ND + k * 32 + lq * 8];
      float4 x0 = *(const float4*)xp;
      float4 x1 = *(const float4*)(xp + 4);
      short8 s;
      s[0]=f2bf(x0.x); s[1]=f2bf(x0.y); s[2]=f2bf(x0.z); s[3]=f2bf(x0.w);
      s[4]=f2bf(x1.x); s[5]=f2bf(x1.y); s[6]=f2bf(x1.z); s[7]=f2bf(x1.w);
      af[ib][k] = s;
    }
  __syncthreads();
  floatx4 acc[4][2];
  #pragma unroll
  for (int ib = 0; ib < 4; ++ib)
    #pragma unroll
    for (int eb = 0; eb < 2; ++eb) acc[ib][eb] = (floatx4){0.f, 0.f, 0.f, 0.f};
  #pragma unroll
  for (int eb = 0; eb < 2; ++eb)
    #pragma unroll
    for (int k = 0; k < 4; ++k){
      short8 bf = *(short8*)&ldsB[(k * 4 + lq) * 1024 + (w * 32 + eb * 16 + lc) * 8];
      #pragma unroll
      for (int ib = 0; ib < 4; ++ib)
        acc[ib][eb] = __builtin_amdgcn_mfma_f32_16x16x32_bf16(af[ib][k], bf, acc[ib][eb], 0, 0, 0);
    }
  __syncthreads();                            // ldsB (B-staging) fully consumed
  #pragma unroll
  for (int ib = 0; ib < 4; ++ib)
    #pragma unroll
    for (int eb = 0; eb < 2; ++eb){
      int d = w * 32 + eb * 16 + lc;
      float bv = bias[d];
      #pragma unroll
      for (int r = 0; r < 4; ++r){
        int n = ib * 16 + lq * 4 + r;         // 0..63 within tile
        ldsB[d * 72 + n] = f2bf(acc[ib][eb][r] + bv);
      }
    }
  __syncthreads();
  #pragma unroll
  for (int c = 0; c < 4; ++c){                // XpT store: [d][n] rows, b128, coalesced
    int g = c * 256 + t; int d = g >> 3, n8 = g & 7;
    short8 v = *(short8*)&ldsB[d * 72 + n8 * 8];
    *(short8*)&XpT[(size_t)(b * ND + d) * NN + i0 + n8 * 8] = v;
  }
  #pragma unroll
  for (int c = 0; c < 4; ++c){                // Xp store: [n][d] rows, b128, coalesced
    int g = c * 256 + t; int n = g >> 4, d8 = g & 15;
    short8 v;
    #pragma unroll
    for (int j = 0; j < 8; ++j) v[j] = ldsB[(d8 * 8 + j) * 72 + n];
    *(short8*)&Xp[(size_t)(b * NN + i0 + n) * ND + d8 * 8] = v;
  }
}

// ---------------- K2: Y[b][h] = Xp @ attn_h  (bf16 out), MFMA vs attnT ------------
__global__ __launch_bounds__(256) void k2_y(const short* __restrict__ Xp,
                                            const short* __restrict__ attnT,
                                            short* __restrict__ Y){
  int bid = blockIdx.x;                       // 512 = 4b * 4h * 32
  int it = bid & 31, h = (bid >> 5) & 3, b = bid >> 7;
  int i0 = it << 6;
  int t = threadIdx.x, w = t >> 6, lane = t & 63, lq = lane >> 4, lc = lane & 15;
  __shared__ __align__(16) short ldsB[16384]; // swizzled [16 dblk][128 e][8]
  const short* Bsrc = attnT + h * 16384;
  #pragma unroll
  for (int c = 0; c < 8; ++c){
    int q = c * 256 + t; int dblk = q >> 7; int e = q & 127;
    *(short8*)&ldsB[q * 8] = *(const short8*)&Bsrc[e * 128 + dblk * 8];
  }
  short8 af[4][4];
  #pragma unroll
  for (int ib = 0; ib < 4; ++ib)
    #pragma unroll
    for (int k = 0; k < 4; ++k)
      af[ib][k] = *(const short8*)&Xp[(b * NN + i0 + ib * 16 + lc) * ND + k * 32 + lq * 8];
  __syncthreads();
  floatx4 acc[4][2];
  #pragma unroll
  for (int ib = 0; ib < 4; ++ib)
    #pragma unroll
    for (int eb = 0; eb < 2; ++eb) acc[ib][eb] = (floatx4){0.f, 0.f, 0.f, 0.f};
  #pragma unroll
  for (int eb = 0; eb < 2; ++eb)
    #pragma unroll
    for (int k = 0; k < 4; ++k){
      short8 bf = *(short8*)&ldsB[(k * 4 + lq) * 1024 + (w * 32 + eb * 16 + lc) * 8];
      #pragma unroll
      for (int ib = 0; ib < 4; ++ib)
        acc[ib][eb] = __builtin_amdgcn_mfma_f32_16x16x32_bf16(af[ib][k], bf, acc[ib][eb], 0, 0, 0);
    }
  #pragma unroll
  for (int ib = 0; ib < 4; ++ib)
    #pragma unroll
    for (int eb = 0; eb < 2; ++eb){
      int e = w * 32 + eb * 16 + lc;
      #pragma unroll
      for (int r = 0; r < 4; ++r){
        int n = i0 + ib * 16 + lq * 4 + r;
        Y[((b * NH + h) * NN + n) * ND + e] = f2bf(acc[ib][eb][r]);
      }
    }
}

// ---------------- K3: fused, WAVE-INDEPENDENT. Each wave owns a 16-m strip/iter:
//   S^T = Xp@Y^T (4 heads) ; Pbar = 0.25*Σ tanh(A*S) ; acc(16i x 128d) += Pbar @ Xp
//   hi/lo split packed into ONE K=32 A-frag (k<16 = hi, k>=16 = lo, B rows dup'd).
//   C->A transform: 8 UNCONDITIONAL ds_bpermute (full exec — convergent!) + 4 selects.
// grid 1024 = (ms 2, b 4, 128 i-tiles of 16 rows); 16 iters of 64 m (16 m/wave).
__global__ __launch_bounds__(256, 3) void k3_fused(const short* __restrict__ Xp,
                                                   const short* __restrict__ XpT,
                                                   const short* __restrict__ Y,
                                                   const float* __restrict__ A,
                                                   float* __restrict__ part){
  int bid = blockIdx.x;
  int it = bid & 127, b = (bid >> 7) & 3, ms = bid >> 9;
  int i0 = it << 4;
  int t = threadIdx.x, w = t >> 6, lane = t & 63, lq = lane >> 4, lc = lane & 15;

  // Y B-frags pinned: all 4 heads, rows i0..i0+16, full 128 d  (64 VGPR)
  short8 yf[4][4];
  #pragma unroll
  for (int h = 0; h < 4; ++h)
    #pragma unroll
    for (int k = 0; k < 4; ++k)
      yf[h][k] = *(const short8*)&Y[((b * NH + h) * NN + i0 + lc) * ND + k * 32 + lq * 8];

  floatx4 acc[8];
  #pragma unroll
  for (int dt = 0; dt < 8; ++dt) acc[dt] = (floatx4){0.f,0.f,0.f,0.f};

  const int mbase = ms << 10;                      // 1024 m per block, wave strip = +w*16
  const short* xr  = Xp  + (size_t)(b * NN + mbase + w * 16 + lc) * ND;
  const float* Ar  = A   + (size_t)(b * NN + i0 + lc) * NN + mbase + w * 16 + lq * 4;
  const short* pvB = XpT + (size_t)(b * ND + lc) * NN + mbase + w * 16 + (lq & 1) * 8;
  const int bpa0 = (((2 * lq) & 3) * 16 + lc) * 4; // bpermute byte addr (src lane *4)
  const int bpa1 = bpa0 + 64;
  const bool hih = (lq < 2);

  // prologue: loads for iter 0
  short8 xpf_c[4];
  #pragma unroll
  for (int k = 0; k < 4; ++k) xpf_c[k] = *(const short8*)&xr[k * 32 + lq * 8];
  floatx4 av_c = *(const floatx4*)Ar;

  for (int itn = 0; itn < 16; ++itn){
    // PV B-frags for this iter (8 d-tiles), issued early; L2-hot XpT
    short8 pvb[8];
    #pragma unroll
    for (int dt = 0; dt < 8; ++dt)
      pvb[dt] = *(const short8*)&pvB[(size_t)dt * 16 * NN];

    // S^T for 4 heads (no LDS), tanh via rcp-sum, head-mean in-register
    float av2[4];
    #pragma unroll
    for (int r = 0; r < 4; ++r) av2[r] = av_c[r] * 2.885390081777926f; // fold 2*log2(e)
    float rs[4] = {0.f, 0.f, 0.f, 0.f};
    #pragma unroll
    for (int h = 0; h < 4; ++h){
      floatx4 S = (floatx4){0.f,0.f,0.f,0.f};
      #pragma unroll
      for (int k = 0; k < 4; ++k)
        S = __builtin_amdgcn_mfma_f32_16x16x32_bf16(xpf_c[k], yf[h][k], S, 0, 0, 0);
      #pragma unroll
      for (int r = 0; r < 4; ++r){
        float e = __builtin_amdgcn_exp2f(av2[r] * S[r]);   // e^{2x}
        rs[r] += __builtin_amdgcn_rcpf(e + 1.f);
      }
    }

    // prefetch next iter's xpf/av
    int adv = (itn < 15) ? 64 : 0;
    xr += (size_t)adv * ND; Ar += adv;
    short8 xpf_n[4];
    #pragma unroll
    for (int k = 0; k < 4; ++k) xpf_n[k] = *(const short8*)&xr[k * 32 + lq * 8];
    floatx4 av_n = *(const floatx4*)Ar;

    // Pbar = 1 - 0.5*rs (== 0.25 * Σ_h tanh); split hi+lo, pack as bf16x2 dwords
    short hb[4], lb[4];
    #pragma unroll
    for (int r = 0; r < 4; ++r){
      float pb = 1.f - 0.5f * rs[r];
      hb[r] = f2bf(pb);
      lb[r] = f2bf(pb - bf2f(hb[r]));
    }
    int ph0 = pack2(hb[0], hb[1]), ph1 = pack2(hb[2], hb[3]);
    int pl0 = pack2(lb[0], lb[1]), pl1 = pack2(lb[2], lb[3]);

    // C-layout -> A-layout, intra-wave. ALL bpermutes run with full exec (convergent);
    // per-lane hi/lo choice applied on the RESULTS via cndmask, never via branches.
    int h0 = __builtin_amdgcn_ds_bpermute(bpa0, ph0);
    int l0 = __builtin_amdgcn_ds_bpermute(bpa0, pl0);
    int h1 = __builtin_amdgcn_ds_bpermute(bpa0, ph1);
    int l1 = __builtin_amdgcn_ds_bpermute(bpa0, pl1);
    int h2 = __builtin_amdgcn_ds_bpermute(bpa1, ph0);
    int l2 = __builtin_amdgcn_ds_bpermute(bpa1, pl0);
    int h3 = __builtin_amdgcn_ds_bpermute(bpa1, ph1);
    int l3 = __builtin_amdgcn_ds_bpermute(bpa1, pl1);
    union { int4 i; short8 s; } cvt;
    cvt.i.x = hih ? h0 : l0;
    cvt.i.y = hih ? h1 : l1;
    cvt.i.z = hih ? h2 : l2;
    cvt.i.w = hih ? h3 : l3;
    short8 pA = cvt.s;

    // PV: acc[dt] += pA(16i x 32k) @ pvb[dt](32k x 16d); 8 independent MFMAs
    #pragma unroll
    for (int dt = 0; dt < 8; ++dt)
      acc[dt] = __builtin_amdgcn_mfma_f32_16x16x32_bf16(pA, pvb[dt], acc[dt], 0, 0, 0);

    pvB += adv;
    #pragma unroll
    for (int k = 0; k < 4; ++k) xpf_c[k] = xpf_n[k];
    av_c = av_n;
  }

  // epilogue: cross-wave reduction of the 4 m-strips via LDS (one barrier, once)
  __shared__ __align__(16) float red[4 * 2112];    // per-wave [16 i][132 pad] f32
  float* myr = red + w * 2112;
  #pragma unroll
  for (int dt = 0; dt < 8; ++dt)
    #pragma unroll
    for (int r = 0; r < 4; ++r)
      myr[(lq * 4 + r) * 132 + dt * 16 + lc] = acc[dt][r];
  __syncthreads();
  int e0 = t * 8; int ii = e0 >> 7; int dd = e0 & 127;
  int base = ii * 132 + dd;
  floatx4 o0 = *(floatx4*)&red[base], o1 = *(floatx4*)&red[base + 4];
  #pragma unroll
  for (int wv = 1; wv < 4; ++wv){
    o0 += *(floatx4*)&red[wv * 2112 + base];
    o1 += *(floatx4*)&red[wv * 2112 + base + 4];
  }
  float* dst = part + (size_t)ms * 1048576 + (size_t)(b * NN + i0 + ii) * ND + dd;
  *(floatx4*)dst = o0;
  *(floatx4*)(dst + 4) = o1;
}

// ---------------- K4: out = relu(relu(p0+p1) + X) ---------------------------------
__global__ void k4_final(const float* __restrict__ part, const float* __restrict__ X,
                         float* __restrict__ out){
  int f = (blockIdx.x * 256 + threadIdx.x) * 4;
  float4 s0 = *(const float4*)(part + f);
  float4 s1 = *(const float4*)(part + 1048576 + f);
  float4 xv = *(const float4*)(X + f);
  float4 o;
  o.x = fmaxf(fmaxf(s0.x + s1.x, 0.f) + xv.x, 0.f);
  o.y = fmaxf(fmaxf(s0.y + s1.y, 0.f) + xv.y, 0.f);
  o.z = fmaxf(fmaxf(s0.z + s1.z, 0.f) + xv.z, 0.f);
  o.w = fmaxf(fmaxf(s0.w + s1.w, 0.f) + xv.w, 0.f);
  *(float4*)(out + f) = o;
}

// ---------------- launch ----------------------------------------------------------
extern "C" void kernel_launch(void* const* d_in, const int* in_sizes, int n_in,
                              void* d_out, int out_size, void* d_ws, size_t ws_size,
                              hipStream_t stream) {
  const float* X    = (const float*)d_in[0];   // [4,2048,128]
  const float* A    = (const float*)d_in[1];   // [4,2048,2048]
  const float* W    = (const float*)d_in[2];   // [128,128]
  const float* bias = (const float*)d_in[3];   // [128]
  const float* attn = (const float*)d_in[4];   // [4,128,128]
  float* out = (float*)d_out;

  // workspace layout
  const size_t OFF_XP    = 0;                          // 2 MB bf16
  const size_t OFF_XPT   = (size_t)2 << 20;            // 2 MB bf16
  const size_t OFF_Y     = (size_t)4 << 20;            // 8 MB bf16
  const size_t OFF_PART  = (size_t)12 << 20;           // 8 MB f32 (2 ms-partials)
  const size_t OFF_WT    = (size_t)20 << 20;           // 32 KB bf16
  const size_t OFF_ATTNT = OFF_WT + 32768;             // 128 KB bf16
  const size_t NEED = OFF_ATTNT + 131072;
  if (ws_size < NEED) return;

  char* ws = (char*)d_ws;
  short* Xp    = (short*)(ws + OFF_XP);
  short* XpT   = (short*)(ws + OFF_XPT);
  short* Y     = (short*)(ws + OFF_Y);
  float* part  = (float*)(ws + OFF_PART);
  short* WT    = (short*)(ws + OFF_WT);
  short* attnT = (short*)(ws + OFF_ATTNT);

  k0_transpose<<<5, 256, 0, stream>>>(W, attn, WT, attnT);
  k1_xp<<<128, 256, 0, stream>>>(X, WT, bias, Xp, XpT);
  k2_y<<<512, 256, 0, stream>>>(Xp, attnT, Y);
  k3_fused<<<1024, 256, 0, stream>>>(Xp, XpT, Y, A, part);
  k4_final<<<1024, 256, 0, stream>>>(part, X, out);
}

// Round 6
// 221.009 us; speedup vs baseline: 1.0412x; 1.0412x over previous
//
#include <hip/hip_runtime.h>

// Problem constants: B=4, N=2048, F=D=128, H=4.
#define NB 4
#define NN 2048
#define ND 128
#define NH 4

typedef short short8 __attribute__((ext_vector_type(8)));
typedef short short4v __attribute__((ext_vector_type(4)));
typedef float floatx4 __attribute__((ext_vector_type(4)));

__device__ __forceinline__ short f2bf(float f){
  unsigned u = __float_as_uint(f);
  u += 0x7FFFu + ((u >> 16) & 1u);   // round-to-nearest-even
  return (short)(u >> 16);
}

// K=16 bf16 MFMA: A/B = 4 bf16 (2 VGPRs), C/D = 4 f32.
__device__ __forceinline__ floatx4 mfma16(short4v a, short4v b, floatx4 c){
#if __has_builtin(__builtin_amdgcn_mfma_f32_16x16x16bf16_1k)
  return __builtin_amdgcn_mfma_f32_16x16x16bf16_1k(a, b, c, 0, 0, 0);
#elif __has_builtin(__builtin_amdgcn_mfma_f32_16x16x16_bf16)
  return __builtin_amdgcn_mfma_f32_16x16x16_bf16(a, b, c, 0, 0, 0);
#else
  floatx4 d = c;
  asm("v_mfma_f32_16x16x16_bf16 %0, %1, %2, %0" : "+v"(d) : "v"(a), "v"(b));
  return d;
#endif
}

// ---------------- K0: WT[d][f] = W[f][d]; attnT[h][e][d] = attn[h][d][e] (bf16) ----
__global__ void k0_transpose(const float* __restrict__ W, const float* __restrict__ attn,
                             short* __restrict__ WT, short* __restrict__ attnT){
  int mat = blockIdx.x;                       // 0 = W, 1..4 = attn heads
  const float* src = (mat == 0) ? W : (attn + (mat - 1) * 16384);
  short* dst = (mat == 0) ? WT : (attnT + (mat - 1) * 16384);
  __shared__ short tile[128 * 130];
  int t = threadIdx.x;
  for (int k = 0; k < 64; ++k){               // coalesced read, transposed LDS write
    int idx = k * 256 + t;
    int r = idx >> 7, c = idx & 127;
    tile[c * 130 + r] = f2bf(src[idx]);
  }
  __syncthreads();
  for (int k = 0; k < 8; ++k){                // coalesced vector write out
    int g = k * 256 + t;
    int r = g >> 4, c8 = g & 15;
    short8 v;
    #pragma unroll
    for (int j = 0; j < 8; ++j) v[j] = tile[r * 130 + c8 * 8 + j];
    *(short8*)&dst[r * 128 + c8 * 8] = v;
  }
}

// ---------------- K1: Xp = X @ W + bias ; writes BOTH Xp and XpT (coalesced) ------
__global__ __launch_bounds__(256) void k1_xp(const float* __restrict__ X,
                                             const short* __restrict__ WT,
                                             const float* __restrict__ bias,
                                             short* __restrict__ Xp,
                                             short* __restrict__ XpT){
  int bid = blockIdx.x;                       // 128 = 4b * 32 i-tiles
  int b = bid >> 5, i0 = (bid & 31) << 6;
  int t = threadIdx.x, w = t >> 6, lane = t & 63, lq = lane >> 4, lc = lane & 15;
  __shared__ __align__(16) short ldsB[16384]; // B-staging, later reused as [128 d][72] tile
  #pragma unroll
  for (int c = 0; c < 8; ++c){
    int q = c * 256 + t; int fblk = q >> 7; int d = q & 127;
    *(short8*)&ldsB[q * 8] = *(const short8*)&WT[d * 128 + fblk * 8];
  }
  short8 af[4][4];
  #pragma unroll
  for (int ib = 0; ib < 4; ++ib)
    #pragma unroll
    for (int k = 0; k < 4; ++k){
      const float* xp = &X[(b * NN + i0 + ib * 16 + lc) * ND + k * 32 + lq * 8];
      float4 x0 = *(const float4*)xp;
      float4 x1 = *(const float4*)(xp + 4);
      short8 s;
      s[0]=f2bf(x0.x); s[1]=f2bf(x0.y); s[2]=f2bf(x0.z); s[3]=f2bf(x0.w);
      s[4]=f2bf(x1.x); s[5]=f2bf(x1.y); s[6]=f2bf(x1.z); s[7]=f2bf(x1.w);
      af[ib][k] = s;
    }
  __syncthreads();
  floatx4 acc[4][2];
  #pragma unroll
  for (int ib = 0; ib < 4; ++ib)
    #pragma unroll
    for (int eb = 0; eb < 2; ++eb) acc[ib][eb] = (floatx4){0.f, 0.f, 0.f, 0.f};
  #pragma unroll
  for (int eb = 0; eb < 2; ++eb)
    #pragma unroll
    for (int k = 0; k < 4; ++k){
      short8 bf = *(short8*)&ldsB[(k * 4 + lq) * 1024 + (w * 32 + eb * 16 + lc) * 8];
      #pragma unroll
      for (int ib = 0; ib < 4; ++ib)
        acc[ib][eb] = __builtin_amdgcn_mfma_f32_16x16x32_bf16(af[ib][k], bf, acc[ib][eb], 0, 0, 0);
    }
  __syncthreads();                            // ldsB (B-staging) fully consumed
  #pragma unroll
  for (int ib = 0; ib < 4; ++ib)
    #pragma unroll
    for (int eb = 0; eb < 2; ++eb){
      int d = w * 32 + eb * 16 + lc;
      float bv = bias[d];
      #pragma unroll
      for (int r = 0; r < 4; ++r){
        int n = ib * 16 + lq * 4 + r;         // 0..63 within tile
        ldsB[d * 72 + n] = f2bf(acc[ib][eb][r] + bv);
      }
    }
  __syncthreads();
  #pragma unroll
  for (int c = 0; c < 4; ++c){                // XpT store: [d][n] rows, b128, coalesced
    int g = c * 256 + t; int d = g >> 3, n8 = g & 7;
    short8 v = *(short8*)&ldsB[d * 72 + n8 * 8];
    *(short8*)&XpT[(size_t)(b * ND + d) * NN + i0 + n8 * 8] = v;
  }
  #pragma unroll
  for (int c = 0; c < 4; ++c){                // Xp store: [n][d] rows, b128, coalesced
    int g = c * 256 + t; int n = g >> 4, d8 = g & 15;
    short8 v;
    #pragma unroll
    for (int j = 0; j < 8; ++j) v[j] = ldsB[(d8 * 8 + j) * 72 + n];
    *(short8*)&Xp[(size_t)(b * NN + i0 + n) * ND + d8 * 8] = v;
  }
}

// ---------------- K2: Y[b][h] = Xp @ attn_h  (bf16 out), MFMA vs attnT ------------
__global__ __launch_bounds__(256) void k2_y(const short* __restrict__ Xp,
                                            const short* __restrict__ attnT,
                                            short* __restrict__ Y){
  int bid = blockIdx.x;                       // 512 = 4b * 4h * 32
  int it = bid & 31, h = (bid >> 5) & 3, b = bid >> 7;
  int i0 = it << 6;
  int t = threadIdx.x, w = t >> 6, lane = t & 63, lq = lane >> 4, lc = lane & 15;
  __shared__ __align__(16) short ldsB[16384]; // swizzled [16 dblk][128 e][8]
  const short* Bsrc = attnT + h * 16384;
  #pragma unroll
  for (int c = 0; c < 8; ++c){
    int q = c * 256 + t; int dblk = q >> 7; int e = q & 127;
    *(short8*)&ldsB[q * 8] = *(const short8*)&Bsrc[e * 128 + dblk * 8];
  }
  short8 af[4][4];
  #pragma unroll
  for (int ib = 0; ib < 4; ++ib)
    #pragma unroll
    for (int k = 0; k < 4; ++k)
      af[ib][k] = *(const short8*)&Xp[(b * NN + i0 + ib * 16 + lc) * ND + k * 32 + lq * 8];
  __syncthreads();
  floatx4 acc[4][2];
  #pragma unroll
  for (int ib = 0; ib < 4; ++ib)
    #pragma unroll
    for (int eb = 0; eb < 2; ++eb) acc[ib][eb] = (floatx4){0.f, 0.f, 0.f, 0.f};
  #pragma unroll
  for (int eb = 0; eb < 2; ++eb)
    #pragma unroll
    for (int k = 0; k < 4; ++k){
      short8 bf = *(short8*)&ldsB[(k * 4 + lq) * 1024 + (w * 32 + eb * 16 + lc) * 8];
      #pragma unroll
      for (int ib = 0; ib < 4; ++ib)
        acc[ib][eb] = __builtin_amdgcn_mfma_f32_16x16x32_bf16(af[ib][k], bf, acc[ib][eb], 0, 0, 0);
    }
  #pragma unroll
  for (int ib = 0; ib < 4; ++ib)
    #pragma unroll
    for (int eb = 0; eb < 2; ++eb){
      int e = w * 32 + eb * 16 + lc;
      #pragma unroll
      for (int r = 0; r < 4; ++r){
        int n = i0 + ib * 16 + lq * 4 + r;
        Y[((b * NH + h) * NN + n) * ND + e] = f2bf(acc[ib][eb][r]);
      }
    }
}

// ---------------- K3: fused, wave-independent, ZERO cross-lane ops in loop.
//   Per wave-iter (16-m strip): S^T = Xp@Y^T (4 heads, 16x16x32) ; tanh-mean ;
//   P lands in C-layout == A-layout of 16x16x16 MFMA -> PV directly, no transform.
//   Deep prefetch: A 2 iters ahead (HBM stream), xpf 1 ahead, pvb intra-iter.
// grid 1024 = (ms 2, b 4, 128 i-tiles); 16 iters of 64 m (16 m per wave).
__global__ __launch_bounds__(256, 2) void k3_fused(const short* __restrict__ Xp,
                                                   const short* __restrict__ XpT,
                                                   const short* __restrict__ Y,
                                                   const float* __restrict__ A,
                                                   float* __restrict__ part){
  int bid = blockIdx.x;
  int it = bid & 127, b = (bid >> 7) & 3, ms = (bid >> 9) & 1;
  int i0 = it << 4;
  int t = threadIdx.x, w = t >> 6, lane = t & 63, lq = lane >> 4, lc = lane & 15;

  // Y B-frags pinned: all 4 heads, rows i0..i0+16, full 128 d  (64 VGPR)
  short8 yf[4][4];
  #pragma unroll
  for (int h = 0; h < 4; ++h)
    #pragma unroll
    for (int k = 0; k < 4; ++k)
      yf[h][k] = *(const short8*)&Y[((b * NH + h) * NN + i0 + lc) * ND + k * 32 + lq * 8];

  floatx4 acc[8];
  #pragma unroll
  for (int dt = 0; dt < 8; ++dt) acc[dt] = (floatx4){0.f,0.f,0.f,0.f};

  const int mbase = ms << 10;                      // 1024 m per block; wave strip +w*16
  const size_t xstep = (size_t)NN * ND;            // per-b
  const short* xbase = Xp  + (size_t)(b * NN + mbase + w * 16 + lc) * ND;
  const float* Ab    = A   + (size_t)(b * NN + i0 + lc) * NN + mbase + w * 16 + lq * 4;
  const short* pvBb  = XpT + (size_t)(b * ND + lc) * NN + mbase + w * 16 + lq * 4;

  // prologue: xpf for iter 0; A for iters 0 and 1
  short8 xpf_c[4];
  #pragma unroll
  for (int k = 0; k < 4; ++k) xpf_c[k] = *(const short8*)&xbase[k * 32 + lq * 8];
  floatx4 av0 = *(const floatx4*)Ab;
  floatx4 av1 = *(const floatx4*)(Ab + 64);

  for (int itn = 0; itn < 16; ++itn){
    // PV B-frags for THIS iter: 8 d-tiles, 8B/lane, issued first (consumed last)
    const short* pv = pvBb + itn * 64;
    short4v pvb[8];
    #pragma unroll
    for (int dt = 0; dt < 8; ++dt)
      pvb[dt] = *(const short4v*)&pv[(size_t)dt * 16 * NN];

    // A prefetch 2 ahead (the only HBM stream)
    int mo2 = itn + 2; if (mo2 > 15) mo2 = 15;
    floatx4 av2 = *(const floatx4*)(Ab + mo2 * 64);

    // xpf prefetch 1 ahead
    int mo1 = itn + 1; if (mo1 > 15) mo1 = 15;
    const short* xrn = xbase + (size_t)(mo1 * 64) * ND;
    short8 xpf_n[4];
    #pragma unroll
    for (int k = 0; k < 4; ++k) xpf_n[k] = *(const short8*)&xrn[k * 32 + lq * 8];

    // S^T for 4 heads (no LDS), tanh via rcp-sum, head-mean in-register
    float avs[4];
    #pragma unroll
    for (int r = 0; r < 4; ++r) avs[r] = av0[r] * 2.885390081777926f; // fold 2*log2(e)
    float rs[4] = {0.f, 0.f, 0.f, 0.f};
    #pragma unroll
    for (int h = 0; h < 4; ++h){
      floatx4 S = (floatx4){0.f,0.f,0.f,0.f};
      #pragma unroll
      for (int k = 0; k < 4; ++k)
        S = __builtin_amdgcn_mfma_f32_16x16x32_bf16(xpf_c[k], yf[h][k], S, 0, 0, 0);
      #pragma unroll
      for (int r = 0; r < 4; ++r){
        float e = __builtin_amdgcn_exp2f(avs[r] * S[r]);   // e^{2x}
        rs[r] += __builtin_amdgcn_rcpf(e + 1.f);
      }
    }

    // Pbar = 1 - 0.5*rs (== 0.25 * Σ_h tanh); C-layout IS the 16x16x16 A-layout.
    short4v pA;
    #pragma unroll
    for (int r = 0; r < 4; ++r) pA[r] = f2bf(1.f - 0.5f * rs[r]);

    // PV: acc[dt] += pA(16i x 16m) @ pvb[dt](16m x 16d); no transform, no barrier
    #pragma unroll
    for (int dt = 0; dt < 8; ++dt)
      acc[dt] = mfma16(pA, pvb[dt], acc[dt]);

    // rotate pipeline registers
    av0 = av1; av1 = av2;
    #pragma unroll
    for (int k = 0; k < 4; ++k) xpf_c[k] = xpf_n[k];
  }

  // epilogue: cross-wave reduction of the 4 m-strips via LDS (one barrier, once)
  __shared__ __align__(16) float red[4 * 2112];    // per-wave [16 i][132 pad] f32
  float* myr = red + w * 2112;
  #pragma unroll
  for (int dt = 0; dt < 8; ++dt)
    #pragma unroll
    for (int r = 0; r < 4; ++r)
      myr[(lq * 4 + r) * 132 + dt * 16 + lc] = acc[dt][r];
  __syncthreads();
  int e0 = t * 8; int ii = e0 >> 7; int dd = e0 & 127;
  int base = ii * 132 + dd;
  floatx4 o0 = *(floatx4*)&red[base], o1 = *(floatx4*)&red[base + 4];
  #pragma unroll
  for (int wv = 1; wv < 4; ++wv){
    o0 += *(floatx4*)&red[wv * 2112 + base];
    o1 += *(floatx4*)&red[wv * 2112 + base + 4];
  }
  float* dst = part + (size_t)ms * 1048576 + (size_t)(b * NN + i0 + ii) * ND + dd;
  *(floatx4*)dst = o0;
  *(floatx4*)(dst + 4) = o1;
}

// ---------------- K4: out = relu(relu(p0+p1) + X) ---------------------------------
__global__ void k4_final(const float* __restrict__ part, const float* __restrict__ X,
                         float* __restrict__ out){
  int f = (blockIdx.x * 256 + threadIdx.x) * 4;
  float4 s0 = *(const float4*)(part + f);
  float4 s1 = *(const float4*)(part + 1048576 + f);
  float4 xv = *(const float4*)(X + f);
  float4 o;
  o.x = fmaxf(fmaxf(s0.x + s1.x, 0.f) + xv.x, 0.f);
  o.y = fmaxf(fmaxf(s0.y + s1.y, 0.f) + xv.y, 0.f);
  o.z = fmaxf(fmaxf(s0.z + s1.z, 0.f) + xv.z, 0.f);
  o.w = fmaxf(fmaxf(s0.w + s1.w, 0.f) + xv.w, 0.f);
  *(float4*)(out + f) = o;
}

// ---------------- launch ----------------------------------------------------------
extern "C" void kernel_launch(void* const* d_in, const int* in_sizes, int n_in,
                              void* d_out, int out_size, void* d_ws, size_t ws_size,
                              hipStream_t stream) {
  const float* X    = (const float*)d_in[0];   // [4,2048,128]
  const float* A    = (const float*)d_in[1];   // [4,2048,2048]
  const float* W    = (const float*)d_in[2];   // [128,128]
  const float* bias = (const float*)d_in[3];   // [128]
  const float* attn = (const float*)d_in[4];   // [4,128,128]
  float* out = (float*)d_out;

  // workspace layout
  const size_t OFF_XP    = 0;                          // 2 MB bf16
  const size_t OFF_XPT   = (size_t)2 << 20;            // 2 MB bf16
  const size_t OFF_Y     = (size_t)4 << 20;            // 8 MB bf16
  const size_t OFF_PART  = (size_t)12 << 20;           // 8 MB f32 (2 ms-partials)
  const size_t OFF_WT    = (size_t)20 << 20;           // 32 KB bf16
  const size_t OFF_ATTNT = OFF_WT + 32768;             // 128 KB bf16
  const size_t NEED = OFF_ATTNT + 131072;
  if (ws_size < NEED) return;

  char* ws = (char*)d_ws;
  short* Xp    = (short*)(ws + OFF_XP);
  short* XpT   = (short*)(ws + OFF_XPT);
  short* Y     = (short*)(ws + OFF_Y);
  float* part  = (float*)(ws + OFF_PART);
  short* WT    = (short*)(ws + OFF_WT);
  short* attnT = (short*)(ws + OFF_ATTNT);

  k0_transpose<<<5, 256, 0, stream>>>(W, attn, WT, attnT);
  k1_xp<<<128, 256, 0, stream>>>(X, WT, bias, Xp, XpT);
  k2_y<<<512, 256, 0, stream>>>(Xp, attnT, Y);
  k3_fused<<<1024, 256, 0, stream>>>(Xp, XpT, Y, A, part);
  k4_final<<<1024, 256, 0, stream>>>(part, X, out);
}